// Round 10
// baseline (281.466 us; speedup 1.0000x reference)
//
#include <hip/hip_runtime.h>
#include <hip/hip_bf16.h>

// Shapes (fixed by setup_inputs): bs=8, v=2048, n=20, inc=64, outc=128, sup=2
#define BS    8
#define V     2048
#define NNB   20
#define INC   64
#define OUTC  128
#define SUP   2
#define NCOL  ((SUP + 1) * OUTC)   // 384
#define SCOL  (SUP * OUTC)         // 256
#define ROWS  (BS * V)             // 16384
#define XPAD  136                  // 128 + 8 bf16 pad -> 2-way-free b128 reads

// Diagnostic repeat factors (R10): identical work per rep; dur_feat = 10*T_feat,
// dur_no = 6*T_no. Revert to 1 after attribution.
#define REP_FEAT 10
#define REP_NO   6

using bf16x8 = __bf16 __attribute__((ext_vector_type(8)));
using bf16x4 = __bf16 __attribute__((ext_vector_type(4)));
using f32x4  = float  __attribute__((ext_vector_type(4)));
using f32x2  = float  __attribute__((ext_vector_type(2)));
using i32x4  = int    __attribute__((ext_vector_type(4)));
using u16x4  = unsigned short __attribute__((ext_vector_type(4)));

#if __has_builtin(__builtin_elementwise_fma)
static __device__ inline f32x2 efma(f32x2 a, f32x2 b, f32x2 c) { return __builtin_elementwise_fma(a, b, c); }
#else
static __device__ inline f32x2 efma(f32x2 a, f32x2 b, f32x2 c) {
    f32x2 r; r[0] = fmaf(a[0], b[0], c[0]); r[1] = fmaf(a[1], b[1], c[1]); return r;
}
#endif
#if __has_builtin(__builtin_elementwise_max)
static __device__ inline f32x2 emax(f32x2 a, f32x2 b) { return __builtin_elementwise_max(a, b); }
#else
static __device__ inline f32x2 emax(f32x2 a, f32x2 b) {
    f32x2 r; r[0] = fmaxf(a[0], b[0]); r[1] = fmaxf(a[1], b[1]); return r;
}
#endif

static __device__ inline bf16x8 cvt8(f32x4 lo, f32x4 hi) {
    bf16x8 r;
    r[0] = (__bf16)lo[0]; r[1] = (__bf16)lo[1]; r[2] = (__bf16)lo[2]; r[3] = (__bf16)lo[3];
    r[4] = (__bf16)hi[0]; r[5] = (__bf16)hi[1]; r[6] = (__bf16)hi[2]; r[7] = (__bf16)hi[3];
    return r;
}

// bf16 (raw u16) -> f32: value = bits << 16
static __device__ inline float b2f(unsigned short u) {
    union { unsigned int i; float f; } c; c.i = ((unsigned int)u) << 16; return c.f;
}

// ---------------------------------------------------------------------------
// K0: prep — WTb bf16 [384][64], Wm1b bf16 [128][128], w2 = Wm2 @ u,
//     u[k] = relu(dw[k]) + relu(dw[128+k])  (valid since dmax >= 0).
// ---------------------------------------------------------------------------
__global__ __launch_bounds__(256) void k_prep(const float* __restrict__ W,
                                              const float* __restrict__ Wm,
                                              const float* __restrict__ dw,
                                              __bf16* __restrict__ WTb,
                                              __bf16* __restrict__ Wm1b,
                                              float* __restrict__ w2) {
    const int b = blockIdx.x;
    if (b < 96) {                       // W [64][384] -> WTb [384][64], coalesced writes
        const int idx = b * 256 + threadIdx.x;      // < 24576
        const int c = idx >> 6, k = idx & 63;
        WTb[idx] = (__bf16)W[k * NCOL + c];
    } else if (b < 160) {               // Wm[:, :128] -> bf16 [o][k]
        const int idx = (b - 96) * 256 + threadIdx.x;   // < 16384
        const int o = idx >> 7, k = idx & 127;
        Wm1b[idx] = (__bf16)Wm[o * SCOL + k];
    } else {                            // u + w2
        __shared__ float u[OUTC];
        const int t = threadIdx.x;
        if (t < OUTC) u[t] = fmaxf(dw[t], 0.f) + fmaxf(dw[OUTC + t], 0.f);
        __syncthreads();
        if (t < OUTC) {
            float s = 0.f;
            for (int k = 0; k < OUTC; ++k) s = fmaf(Wm[t * SCOL + OUTC + k], u[k], s);
            w2[t] = s;
        }
    }
}

// ---------------------------------------------------------------------------
// K1: feat = fm @ W + bias (MFMA bf16). Block = 4 waves, 32 rows x 384 cols.
// center -> f32, support -> bf16 (consumed by k_no gathers).
// DIAGNOSTIC: whole body repeated REP_FEAT x (idempotent).
// ---------------------------------------------------------------------------
__global__ __launch_bounds__(256) void k_feat(const float* __restrict__ fm,
                                              const __bf16* __restrict__ WTb,
                                              const float* __restrict__ bias,
                                              float* __restrict__ center,
                                              __bf16* __restrict__ supb) {
    const int row0 = blockIdx.x * 32;
    const int wid = threadIdx.x >> 6, lane = threadIdx.x & 63;
    const int ln = lane & 15, lg = lane >> 4;
    const int cbase = wid * 96;

    for (int rep = 0; rep < REP_FEAT; ++rep) {
        asm volatile("" ::: "memory");   // block cross-rep load CSE/hoist

        bf16x8 a[2][2];
#pragma unroll
        for (int rs = 0; rs < 2; ++rs) {
            const float* ap = fm + (size_t)(row0 + rs * 16 + ln) * INC + lg * 8;
            a[rs][0] = cvt8(*(const f32x4*)(ap +  0), *(const f32x4*)(ap +  4));
            a[rs][1] = cvt8(*(const f32x4*)(ap + 32), *(const f32x4*)(ap + 36));
        }

        f32x4 acc[2][6];
#pragma unroll
        for (int t = 0; t < 6; ++t) {
            const float bb = bias[cbase + t * 16 + ln];
            acc[0][t] = (f32x4){bb, bb, bb, bb};
            acc[1][t] = acc[0][t];
        }

        const __bf16* bp = WTb + (size_t)(cbase + ln) * INC + lg * 8;
#pragma unroll
        for (int t = 0; t < 6; ++t) {
            const bf16x8 b0 = *(const bf16x8*)(bp + t * 16 * INC);
            const bf16x8 b1 = *(const bf16x8*)(bp + t * 16 * INC + 32);
            acc[0][t] = __builtin_amdgcn_mfma_f32_16x16x32_bf16(a[0][0], b0, acc[0][t], 0, 0, 0);
            acc[0][t] = __builtin_amdgcn_mfma_f32_16x16x32_bf16(a[0][1], b1, acc[0][t], 0, 0, 0);
            acc[1][t] = __builtin_amdgcn_mfma_f32_16x16x32_bf16(a[1][0], b0, acc[1][t], 0, 0, 0);
            acc[1][t] = __builtin_amdgcn_mfma_f32_16x16x32_bf16(a[1][1], b1, acc[1][t], 0, 0, 0);
        }

        // C: col = lane&15, row = (lane>>4)*4 + r
#pragma unroll
        for (int rs = 0; rs < 2; ++rs) {
            const int r0 = row0 + rs * 16 + lg * 4;
#pragma unroll
            for (int t = 0; t < 6; ++t) {
                const int col = cbase + t * 16 + ln;
                if (col < OUTC) {
#pragma unroll
                    for (int r = 0; r < 4; ++r)
                        center[(size_t)(r0 + r) * OUTC + col] = acc[rs][t][r];
                } else {
                    const int sc = col - OUTC;
#pragma unroll
                    for (int r = 0; r < 4; ++r)
                        supb[(size_t)(r0 + r) * SCOL + sc] = (__bf16)acc[rs][t][r];
                }
            }
        }
    }
}

// ---------------------------------------------------------------------------
// K2 (merged neigh+out): block = 16 vertices, grid 1024 (4 blk/CU).
// DIAGNOSTIC: phases N+G repeated REP_NO x (idempotent; barrier at rep end
// protects Xl/dl reuse).
// ---------------------------------------------------------------------------
__global__ __launch_bounds__(256, 4) void k_no(const int*   __restrict__ nbr,
                                               const float* __restrict__ verts,
                                               const float* __restrict__ dirs,
                                               const float* __restrict__ center,
                                               const __bf16* __restrict__ supb,
                                               const __bf16* __restrict__ Wm1b,
                                               const float* __restrict__ w2,
                                               const float* __restrict__ mb,
                                               float* __restrict__ out) {
    const int bid   = blockIdx.x;
    const int batch = bid & 7;
    const int chunk = bid >> 3;            // 0..127
    const int u0    = chunk * 16;
    const int bV    = batch * V;
    const int tid   = threadIdx.x;
    const int wid   = tid >> 6;
    const int lane  = tid & 63;
    const int half  = lane >> 5;
    const int sl    = lane & 31;
    const int c0    = sl * 4;
    const int ln    = lane & 15, lg = lane >> 4;

    __shared__ __bf16 Xl[16][XPAD];        // 4.25 KB
    __shared__ float  dl[16];

    // ---- normalized spatial directions (rep-invariant, hoisted)
    f32x4 A0 = *(const f32x4*)(dirs +            c0);
    f32x4 A1 = *(const f32x4*)(dirs + SCOL +     c0);
    f32x4 A2 = *(const f32x4*)(dirs + 2*SCOL +   c0);
    f32x4 B0 = *(const f32x4*)(dirs +            OUTC + c0);
    f32x4 B1 = *(const f32x4*)(dirs + SCOL +     OUTC + c0);
    f32x4 B2 = *(const f32x4*)(dirs + 2*SCOL +   OUTC + c0);
#pragma unroll
    for (int j = 0; j < 4; ++j) {
        float inv = __builtin_amdgcn_rsqf(fmaxf(fmaf(A0[j], A0[j], fmaf(A1[j], A1[j], A2[j]*A2[j])), 1e-24f));
        A0[j] *= inv; A1[j] *= inv; A2[j] *= inv;
        inv = __builtin_amdgcn_rsqf(fmaxf(fmaf(B0[j], B0[j], fmaf(B1[j], B1[j], B2[j]*B2[j])), 1e-24f));
        B0[j] *= inv; B1[j] *= inv; B2[j] *= inv;
    }
    const f32x2 ax0 = {A0[0], A0[1]}, ax1 = {A0[2], A0[3]};
    const f32x2 ay0 = {A1[0], A1[1]}, ay1 = {A1[2], A1[3]};
    const f32x2 az0 = {A2[0], A2[1]}, az1 = {A2[2], A2[3]};
    const f32x2 bx0 = {B0[0], B0[1]}, bx1 = {B0[2], B0[3]};
    const f32x2 by0 = {B1[0], B1[1]}, by1 = {B1[2], B1[3]};
    const f32x2 bz0 = {B2[0], B2[1]}, bz1 = {B2[2], B2[3]};
    const f32x2 zero = {0.f, 0.f};

    const __bf16* supBase = supb + (size_t)bV * SCOL + c0;

    for (int rep = 0; rep < REP_NO; ++rep) {
        asm volatile("" ::: "memory");   // block cross-rep load CSE/hoist

        // ---- Phase N: neighbor max over 2 passes (2 vertices/wave each)
#pragma unroll
        for (int p = 0; p < 2; ++p) {
            const int ul  = p * 8 + wid * 2 + half;      // 0..15
            const int row = bV + u0 + ul;

            const float vx = verts[row * 3 + 0];
            const float vy = verts[row * 3 + 1];
            const float vz = verts[row * 3 + 2];

            int gs[NNB];
            {
                const i32x4* np4 = reinterpret_cast<const i32x4*>(nbr + (size_t)row * NNB);
#pragma unroll
                for (int t = 0; t < 5; ++t) {
                    const i32x4 g4 = np4[t];
                    gs[t*4+0] = g4[0]; gs[t*4+1] = g4[1]; gs[t*4+2] = g4[2]; gs[t*4+3] = g4[3];
                }
            }

            f32x2 mA0 = {-INFINITY, -INFINITY}, mA1 = mA0, mB0 = mA0, mB1 = mA0;
            float d2max = 0.f;

#pragma unroll
            for (int t = 0; t < 4; ++t) {
                // issue 10 support gathers + 5 vertex reads for 5 neighbors
                u16x4 s0r[5], s1r[5];
                float px[5], py[5], pz[5];
#pragma unroll
                for (int q = 0; q < 5; ++q) {
                    const int g = gs[t * 5 + q];
                    const __bf16* sg = supBase + (size_t)g * SCOL;
                    s0r[q] = *(const u16x4*)(sg);
                    s1r[q] = *(const u16x4*)(sg + OUTC);
                    const float* vp = verts + (size_t)(bV + g) * 3;
                    px[q] = vp[0]; py[q] = vp[1]; pz[q] = vp[2];
                }
#pragma unroll
                for (int q = 0; q < 5; ++q) {
                    const float dx = px[q] - vx, dy = py[q] - vy, dz = pz[q] - vz;
                    const float d2 = fmaf(dx, dx, fmaf(dy, dy, dz * dz));
                    d2max = fmaxf(d2max, d2);
                    const float inv = __builtin_amdgcn_rsqf(fmaxf(d2, 1e-24f));  // == 1/max(dist,1e-12)
                    const f32x2 nX = {dx * inv, dx * inv};
                    const f32x2 nY = {dy * inv, dy * inv};
                    const f32x2 nZ = {dz * inv, dz * inv};

                    const f32x2 s0lo = {b2f(s0r[q][0]), b2f(s0r[q][1])};
                    const f32x2 s0hi = {b2f(s0r[q][2]), b2f(s0r[q][3])};
                    const f32x2 s1lo = {b2f(s1r[q][0]), b2f(s1r[q][1])};
                    const f32x2 s1hi = {b2f(s1r[q][2]), b2f(s1r[q][3])};

                    const f32x2 tA0 = emax(efma(nZ, az0, efma(nY, ay0, nX * ax0)), zero);
                    const f32x2 tA1 = emax(efma(nZ, az1, efma(nY, ay1, nX * ax1)), zero);
                    const f32x2 tB0 = emax(efma(nZ, bz0, efma(nY, by0, nX * bx0)), zero);
                    const f32x2 tB1 = emax(efma(nZ, bz1, efma(nY, by1, nX * bx1)), zero);
                    mA0 = emax(mA0, tA0 * s0lo);
                    mA1 = emax(mA1, tA1 * s0hi);
                    mB0 = emax(mB0, tB0 * s1lo);
                    mB1 = emax(mB1, tB1 * s1hi);
                }
            }

            const f32x4 cc = *(const f32x4*)(center + (size_t)row * OUTC + c0);
            const f32x2 f01 = (f32x2){cc[0], cc[1]} + mA0 + mB0;
            const f32x2 f23 = (f32x2){cc[2], cc[3]} + mA1 + mB1;
            bf16x4 fx;
            fx[0] = (__bf16)f01[0]; fx[1] = (__bf16)f01[1];
            fx[2] = (__bf16)f23[0]; fx[3] = (__bf16)f23[1];
            *(bf16x4*)(&Xl[ul][c0]) = fx;
            if (sl == 0) dl[ul] = sqrtf(d2max);
        }
        __syncthreads();

        // ---- Phase G: out = Xl @ Wm1b^T + dmax*w2 + mb (MFMA, K=128)
        {
            const int cb = wid * 32;

            bf16x8 a[4];
#pragma unroll
            for (int kf = 0; kf < 4; ++kf)
                a[kf] = *(const bf16x8*)(&Xl[ln][lg * 8 + kf * 32]);

            f32x4 acc[2];
            acc[0] = (f32x4)0.f; acc[1] = (f32x4)0.f;

            const __bf16* bp = Wm1b + (size_t)(cb + ln) * OUTC + lg * 8;
#pragma unroll
            for (int t = 0; t < 2; ++t) {
#pragma unroll
                for (int kf = 0; kf < 4; ++kf) {
                    const bf16x8 b = *(const bf16x8*)(bp + t * 16 * OUTC + kf * 32);
                    acc[t] = __builtin_amdgcn_mfma_f32_16x16x32_bf16(a[kf], b, acc[t], 0, 0, 0);
                }
            }

            float dm[4];
#pragma unroll
            for (int r = 0; r < 4; ++r) dm[r] = dl[lg * 4 + r];

            const int rowg0 = bV + u0 + lg * 4;
#pragma unroll
            for (int t = 0; t < 2; ++t) {
                const int col = cb + t * 16 + ln;
                const float w2c = w2[col];
                const float bb  = mb[col];
#pragma unroll
                for (int r = 0; r < 4; ++r)
                    out[(size_t)(rowg0 + r) * OUTC + col] = fmaf(dm[r], w2c, acc[t][r] + bb);
            }
        }
        __syncthreads();   // protect Xl/dl reuse across reps
    }
}

// ---------------------------------------------------------------------------
extern "C" void kernel_launch(void* const* d_in, const int* in_sizes, int n_in,
                              void* d_out, int out_size, void* d_ws, size_t ws_size,
                              hipStream_t stream) {
    const int*   nbr   = (const int*)  d_in[0];
    const float* verts = (const float*)d_in[1];
    const float* fm    = (const float*)d_in[2];
    const float* W     = (const float*)d_in[3];
    const float* bias  = (const float*)d_in[4];
    const float* dirs  = (const float*)d_in[5];
    const float* dw    = (const float*)d_in[6];
    const float* Wm    = (const float*)d_in[7];
    const float* mb    = (const float*)d_in[8];
    float* out = (float*)d_out;

    // workspace layout (all 16B-aligned)
    float*  center  = (float*)d_ws;                               // 16384*128 f32
    __bf16* supb    = (__bf16*)(center + (size_t)ROWS * OUTC);    // 16384*256 bf16
    __bf16* WTb     = supb + (size_t)ROWS * SCOL;                 // 384*64 bf16
    __bf16* Wm1b    = WTb + NCOL * INC;                           // 128*128 bf16
    float*  w2      = (float*)(Wm1b + OUTC * OUTC);               // 128 f32

    k_prep <<<161,        256, 0, stream>>>(W, Wm, dw, WTb, Wm1b, w2);
    k_feat <<<ROWS / 32,  256, 0, stream>>>(fm, WTb, bias, center, supb);
    k_no   <<<ROWS / 16,  256, 0, stream>>>(nbr, verts, dirs, center, supb, Wm1b, w2, mb, out);
}

// Round 11
// 243.762 us; speedup vs baseline: 1.1547x; 1.1547x over previous
//
#include <hip/hip_runtime.h>
#include <hip/hip_bf16.h>

// Shapes (fixed by setup_inputs): bs=8, v=2048, n=20, inc=64, outc=128, sup=2
#define BS    8
#define V     2048
#define NNB   20
#define INC   64
#define OUTC  128
#define SUP   2
#define NCOL  ((SUP + 1) * OUTC)   // 384
#define SCOL  (SUP * OUTC)         // 256
#define ROWS  (BS * V)             // 16384
#define XPAD  136                  // 128 + 8 bf16 pad -> 2-way-free b128 reads

// Packed support row: [256 bf16 support | 3 f32 xyz | 1 f32 pad] = 528 B
#define SROW_B   528
#define SROW_E   264               // in bf16 elements
#define XYZ_OFF  512               // byte offset of xyz within row

using bf16x8 = __bf16 __attribute__((ext_vector_type(8)));
using bf16x4 = __bf16 __attribute__((ext_vector_type(4)));
using f32x4  = float  __attribute__((ext_vector_type(4)));
using f32x2  = float  __attribute__((ext_vector_type(2)));
using i32x4  = int    __attribute__((ext_vector_type(4)));
using u16x4  = unsigned short __attribute__((ext_vector_type(4)));

#if __has_builtin(__builtin_elementwise_fma)
static __device__ inline f32x2 efma(f32x2 a, f32x2 b, f32x2 c) { return __builtin_elementwise_fma(a, b, c); }
#else
static __device__ inline f32x2 efma(f32x2 a, f32x2 b, f32x2 c) {
    f32x2 r; r[0] = fmaf(a[0], b[0], c[0]); r[1] = fmaf(a[1], b[1], c[1]); return r;
}
#endif
#if __has_builtin(__builtin_elementwise_max)
static __device__ inline f32x2 emax(f32x2 a, f32x2 b) { return __builtin_elementwise_max(a, b); }
#else
static __device__ inline f32x2 emax(f32x2 a, f32x2 b) {
    f32x2 r; r[0] = fmaxf(a[0], b[0]); r[1] = fmaxf(a[1], b[1]); return r;
}
#endif

static __device__ inline bf16x8 cvt8(f32x4 lo, f32x4 hi) {
    bf16x8 r;
    r[0] = (__bf16)lo[0]; r[1] = (__bf16)lo[1]; r[2] = (__bf16)lo[2]; r[3] = (__bf16)lo[3];
    r[4] = (__bf16)hi[0]; r[5] = (__bf16)hi[1]; r[6] = (__bf16)hi[2]; r[7] = (__bf16)hi[3];
    return r;
}

// bf16 (raw u16) -> f32: value = bits << 16
static __device__ inline float b2f(unsigned short u) {
    union { unsigned int i; float f; } c; c.i = ((unsigned int)u) << 16; return c.f;
}

// ---------------------------------------------------------------------------
// K0: prep — WTb bf16 [384][64], Wm1b bf16 [128][128], w2 = Wm2 @ u,
//     xyz pack into supx rows. u[k] = relu(dw[k]) + relu(dw[128+k]).
// ---------------------------------------------------------------------------
__global__ __launch_bounds__(256) void k_prep(const float* __restrict__ W,
                                              const float* __restrict__ Wm,
                                              const float* __restrict__ dw,
                                              const float* __restrict__ verts,
                                              __bf16* __restrict__ WTb,
                                              __bf16* __restrict__ Wm1b,
                                              float* __restrict__ w2,
                                              __bf16* __restrict__ supx) {
    const int b = blockIdx.x;
    if (b < 96) {                       // W [64][384] -> WTb [384][64], coalesced writes
        const int idx = b * 256 + threadIdx.x;      // < 24576
        const int c = idx >> 6, k = idx & 63;
        WTb[idx] = (__bf16)W[k * NCOL + c];
    } else if (b < 160) {               // Wm[:, :128] -> bf16 [o][k]
        const int idx = (b - 96) * 256 + threadIdx.x;   // < 16384
        const int o = idx >> 7, k = idx & 127;
        Wm1b[idx] = (__bf16)Wm[o * SCOL + k];
    } else if (b == 160) {              // u + w2
        __shared__ float u[OUTC];
        const int t = threadIdx.x;
        if (t < OUTC) u[t] = fmaxf(dw[t], 0.f) + fmaxf(dw[OUTC + t], 0.f);
        __syncthreads();
        if (t < OUTC) {
            float s = 0.f;
            for (int k = 0; k < OUTC; ++k) s = fmaf(Wm[t * SCOL + OUTC + k], u[k], s);
            w2[t] = s;
        }
    } else {                            // xyz pack: one row per thread
        const int idx = (b - 161) * 256 + threadIdx.x;  // < 16384
        f32x4 wv;
        wv[0] = verts[(size_t)idx * 3 + 0];
        wv[1] = verts[(size_t)idx * 3 + 1];
        wv[2] = verts[(size_t)idx * 3 + 2];
        wv[3] = 0.f;
        *(f32x4*)((char*)supx + (size_t)idx * SROW_B + XYZ_OFF) = wv;
    }
}

// ---------------------------------------------------------------------------
// K1: feat = fm @ W + bias (MFMA bf16). Block = 4 waves, 32 rows x 384 cols.
// center -> f32; support -> bf16 into packed supx rows (stride 264 elems).
// ---------------------------------------------------------------------------
__global__ __launch_bounds__(256) void k_feat(const float* __restrict__ fm,
                                              const __bf16* __restrict__ WTb,
                                              const float* __restrict__ bias,
                                              float* __restrict__ center,
                                              __bf16* __restrict__ supx) {
    const int row0 = blockIdx.x * 32;
    const int wid = threadIdx.x >> 6, lane = threadIdx.x & 63;
    const int ln = lane & 15, lg = lane >> 4;
    const int cbase = wid * 96;

    bf16x8 a[2][2];
#pragma unroll
    for (int rs = 0; rs < 2; ++rs) {
        const float* ap = fm + (size_t)(row0 + rs * 16 + ln) * INC + lg * 8;
        a[rs][0] = cvt8(*(const f32x4*)(ap +  0), *(const f32x4*)(ap +  4));
        a[rs][1] = cvt8(*(const f32x4*)(ap + 32), *(const f32x4*)(ap + 36));
    }

    f32x4 acc[2][6];
#pragma unroll
    for (int t = 0; t < 6; ++t) {
        const float bb = bias[cbase + t * 16 + ln];
        acc[0][t] = (f32x4){bb, bb, bb, bb};
        acc[1][t] = acc[0][t];
    }

    const __bf16* bp = WTb + (size_t)(cbase + ln) * INC + lg * 8;
#pragma unroll
    for (int t = 0; t < 6; ++t) {
        const bf16x8 b0 = *(const bf16x8*)(bp + t * 16 * INC);
        const bf16x8 b1 = *(const bf16x8*)(bp + t * 16 * INC + 32);
        acc[0][t] = __builtin_amdgcn_mfma_f32_16x16x32_bf16(a[0][0], b0, acc[0][t], 0, 0, 0);
        acc[0][t] = __builtin_amdgcn_mfma_f32_16x16x32_bf16(a[0][1], b1, acc[0][t], 0, 0, 0);
        acc[1][t] = __builtin_amdgcn_mfma_f32_16x16x32_bf16(a[1][0], b0, acc[1][t], 0, 0, 0);
        acc[1][t] = __builtin_amdgcn_mfma_f32_16x16x32_bf16(a[1][1], b1, acc[1][t], 0, 0, 0);
    }

    // C: col = lane&15, row = (lane>>4)*4 + r
#pragma unroll
    for (int rs = 0; rs < 2; ++rs) {
        const int r0 = row0 + rs * 16 + lg * 4;
#pragma unroll
        for (int t = 0; t < 6; ++t) {
            const int col = cbase + t * 16 + ln;
            if (col < OUTC) {
#pragma unroll
                for (int r = 0; r < 4; ++r)
                    center[(size_t)(r0 + r) * OUTC + col] = acc[rs][t][r];
            } else {
                const int sc = col - OUTC;
#pragma unroll
                for (int r = 0; r < 4; ++r)
                    supx[(size_t)(r0 + r) * SROW_E + sc] = (__bf16)acc[rs][t][r];
            }
        }
    }
}

// ---------------------------------------------------------------------------
// K2 (merged neigh+out): block = 8 vertices, grid 2048 (8 blk/CU @ 64 VGPR).
// Packed supx: per neighbor ONE base address serves sup-half-A (+0),
// sup-half-B (+256) and xyz (+512) via immediate offsets.
// Phase N: 4 waves x 2 vertices (32 lanes each), lane sl owns cols sl*4..+3
//   of each support half; fuse (bf16) -> LDS Xl, dmax -> dl.
// Phase G: out = Xl @ Wm1b^T + dmax*w2 + mb; M=16 MFMA with 8 valid rows
//   (rows 8-15 garbage, never stored - MFMA rows are independent).
// batch = bid&7 XCD swizzle.
// ---------------------------------------------------------------------------
__global__ __launch_bounds__(256, 8) void k_no(const int*   __restrict__ nbr,
                                               const float* __restrict__ dirs,
                                               const float* __restrict__ center,
                                               const __bf16* __restrict__ supx,
                                               const __bf16* __restrict__ Wm1b,
                                               const float* __restrict__ w2,
                                               const float* __restrict__ mb,
                                               float* __restrict__ out) {
    const int bid   = blockIdx.x;
    const int batch = bid & 7;
    const int chunk = bid >> 3;            // 0..255
    const int u0    = chunk * 8;
    const int bV    = batch * V;
    const int tid   = threadIdx.x;
    const int wid   = tid >> 6;
    const int lane  = tid & 63;
    const int half  = lane >> 5;
    const int sl    = lane & 31;
    const int c0    = sl * 4;
    const int ln    = lane & 15, lg = lane >> 4;

    __shared__ __bf16 Xl[16][XPAD];        // rows 0..7 valid
    __shared__ float  dl[16];

    // ---- normalized spatial directions
    f32x4 A0 = *(const f32x4*)(dirs +            c0);
    f32x4 A1 = *(const f32x4*)(dirs + SCOL +     c0);
    f32x4 A2 = *(const f32x4*)(dirs + 2*SCOL +   c0);
    f32x4 B0 = *(const f32x4*)(dirs +            OUTC + c0);
    f32x4 B1 = *(const f32x4*)(dirs + SCOL +     OUTC + c0);
    f32x4 B2 = *(const f32x4*)(dirs + 2*SCOL +   OUTC + c0);
#pragma unroll
    for (int j = 0; j < 4; ++j) {
        float inv = __builtin_amdgcn_rsqf(fmaxf(fmaf(A0[j], A0[j], fmaf(A1[j], A1[j], A2[j]*A2[j])), 1e-24f));
        A0[j] *= inv; A1[j] *= inv; A2[j] *= inv;
        inv = __builtin_amdgcn_rsqf(fmaxf(fmaf(B0[j], B0[j], fmaf(B1[j], B1[j], B2[j]*B2[j])), 1e-24f));
        B0[j] *= inv; B1[j] *= inv; B2[j] *= inv;
    }
    const f32x2 ax0 = {A0[0], A0[1]}, ax1 = {A0[2], A0[3]};
    const f32x2 ay0 = {A1[0], A1[1]}, ay1 = {A1[2], A1[3]};
    const f32x2 az0 = {A2[0], A2[1]}, az1 = {A2[2], A2[3]};
    const f32x2 bx0 = {B0[0], B0[1]}, bx1 = {B0[2], B0[3]};
    const f32x2 by0 = {B1[0], B1[1]}, by1 = {B1[2], B1[3]};
    const f32x2 bz0 = {B2[0], B2[1]}, bz1 = {B2[2], B2[3]};
    const f32x2 zero = {0.f, 0.f};

    const char* supB = (const char*)supx + (size_t)bV * SROW_B;

    // ---- Phase N: one pass, 2 vertices/wave
    {
        const int ul  = wid * 2 + half;        // 0..7
        const int u   = u0 + ul;
        const int row = bV + u;

        const f32x4 self = *(const f32x4*)(supB + (size_t)u * SROW_B + XYZ_OFF);
        const float vx = self[0], vy = self[1], vz = self[2];

        int gs[NNB];
        {
            const i32x4* np4 = reinterpret_cast<const i32x4*>(nbr + (size_t)row * NNB);
#pragma unroll
            for (int t = 0; t < 5; ++t) {
                const i32x4 g4 = np4[t];
                gs[t*4+0] = g4[0]; gs[t*4+1] = g4[1]; gs[t*4+2] = g4[2]; gs[t*4+3] = g4[3];
            }
        }

        f32x2 mA0 = {-INFINITY, -INFINITY}, mA1 = mA0, mB0 = mA0, mB1 = mA0;
        float d2max = 0.f;

#pragma unroll
        for (int t = 0; t < 5; ++t) {
            // 4 neighbors: one base address each, 3 loads via imm offsets
            u16x4 s0r[4], s1r[4];
            f32x4 nxyz[4];
#pragma unroll
            for (int q = 0; q < 4; ++q) {
                const char* nb = supB + (size_t)gs[t * 4 + q] * SROW_B + (size_t)(sl * 8);
                s0r[q]  = *(const u16x4*)(nb);
                s1r[q]  = *(const u16x4*)(nb + 256);
                nxyz[q] = *(const f32x4*)(supB + (size_t)gs[t * 4 + q] * SROW_B + XYZ_OFF);
            }
#pragma unroll
            for (int q = 0; q < 4; ++q) {
                const float dx = nxyz[q][0] - vx, dy = nxyz[q][1] - vy, dz = nxyz[q][2] - vz;
                const float d2 = fmaf(dx, dx, fmaf(dy, dy, dz * dz));
                d2max = fmaxf(d2max, d2);
                const float inv = __builtin_amdgcn_rsqf(fmaxf(d2, 1e-24f));  // == 1/max(dist,1e-12)
                const f32x2 nX = {dx * inv, dx * inv};
                const f32x2 nY = {dy * inv, dy * inv};
                const f32x2 nZ = {dz * inv, dz * inv};

                const f32x2 s0lo = {b2f(s0r[q][0]), b2f(s0r[q][1])};
                const f32x2 s0hi = {b2f(s0r[q][2]), b2f(s0r[q][3])};
                const f32x2 s1lo = {b2f(s1r[q][0]), b2f(s1r[q][1])};
                const f32x2 s1hi = {b2f(s1r[q][2]), b2f(s1r[q][3])};

                const f32x2 tA0 = emax(efma(nZ, az0, efma(nY, ay0, nX * ax0)), zero);
                const f32x2 tA1 = emax(efma(nZ, az1, efma(nY, ay1, nX * ax1)), zero);
                const f32x2 tB0 = emax(efma(nZ, bz0, efma(nY, by0, nX * bx0)), zero);
                const f32x2 tB1 = emax(efma(nZ, bz1, efma(nY, by1, nX * bx1)), zero);
                mA0 = emax(mA0, tA0 * s0lo);
                mA1 = emax(mA1, tA1 * s0hi);
                mB0 = emax(mB0, tB0 * s1lo);
                mB1 = emax(mB1, tB1 * s1hi);
            }
        }

        const f32x4 cc = *(const f32x4*)(center + (size_t)row * OUTC + c0);
        const f32x2 f01 = (f32x2){cc[0], cc[1]} + mA0 + mB0;
        const f32x2 f23 = (f32x2){cc[2], cc[3]} + mA1 + mB1;
        bf16x4 fx;
        fx[0] = (__bf16)f01[0]; fx[1] = (__bf16)f01[1];
        fx[2] = (__bf16)f23[0]; fx[3] = (__bf16)f23[1];
        *(bf16x4*)(&Xl[ul][c0]) = fx;
        if (sl == 0) dl[ul] = sqrtf(d2max);
    }
    __syncthreads();

    // ---- Phase G: out = Xl @ Wm1b^T + dmax*w2 + mb (MFMA, K=128)
    // wave wid -> cols wid*32..+31 (2 tiles). Rows 8-15 of A are garbage
    // (never stored; MFMA output rows are independent).
    {
        const int cb = wid * 32;

        bf16x8 a[4];
#pragma unroll
        for (int kf = 0; kf < 4; ++kf)
            a[kf] = *(const bf16x8*)(&Xl[ln][lg * 8 + kf * 32]);

        f32x4 acc[2];
        acc[0] = (f32x4)0.f; acc[1] = (f32x4)0.f;

        const __bf16* bp = Wm1b + (size_t)(cb + ln) * OUTC + lg * 8;
#pragma unroll
        for (int t = 0; t < 2; ++t) {
#pragma unroll
            for (int kf = 0; kf < 4; ++kf) {
                const bf16x8 b = *(const bf16x8*)(bp + t * 16 * OUTC + kf * 32);
                acc[t] = __builtin_amdgcn_mfma_f32_16x16x32_bf16(a[kf], b, acc[t], 0, 0, 0);
            }
        }

        if (lg < 2) {                       // valid output rows 0..7
            float dm[4];
#pragma unroll
            for (int r = 0; r < 4; ++r) dm[r] = dl[lg * 4 + r];

            const int rowg0 = bV + u0 + lg * 4;
#pragma unroll
            for (int t = 0; t < 2; ++t) {
                const int col = cb + t * 16 + ln;
                const float w2c = w2[col];
                const float bb  = mb[col];
#pragma unroll
                for (int r = 0; r < 4; ++r)
                    out[(size_t)(rowg0 + r) * OUTC + col] = fmaf(dm[r], w2c, acc[t][r] + bb);
            }
        }
    }
}

// ---------------------------------------------------------------------------
extern "C" void kernel_launch(void* const* d_in, const int* in_sizes, int n_in,
                              void* d_out, int out_size, void* d_ws, size_t ws_size,
                              hipStream_t stream) {
    const int*   nbr   = (const int*)  d_in[0];
    const float* verts = (const float*)d_in[1];
    const float* fm    = (const float*)d_in[2];
    const float* W     = (const float*)d_in[3];
    const float* bias  = (const float*)d_in[4];
    const float* dirs  = (const float*)d_in[5];
    const float* dw    = (const float*)d_in[6];
    const float* Wm    = (const float*)d_in[7];
    const float* mb    = (const float*)d_in[8];
    float* out = (float*)d_out;

    // workspace layout (all 16B-aligned)
    float*  center  = (float*)d_ws;                               // 16384*128 f32 (8 MB)
    __bf16* supx    = (__bf16*)(center + (size_t)ROWS * OUTC);    // 16384*264 bf16 (8.65 MB, packed)
    __bf16* WTb     = supx + (size_t)ROWS * SROW_E;               // 384*64 bf16
    __bf16* Wm1b    = WTb + NCOL * INC;                           // 128*128 bf16
    float*  w2      = (float*)(Wm1b + OUTC * OUTC);               // 128 f32

    k_prep <<<225,        256, 0, stream>>>(W, Wm, dw, verts, WTb, Wm1b, w2, supx);
    k_feat <<<ROWS / 32,  256, 0, stream>>>(fm, WTb, bias, center, supx);
    k_no   <<<ROWS / 8,   256, 0, stream>>>(nbr, dirs, center, supx, Wm1b, w2, mb, out);
}

// Round 12
// 121.494 us; speedup vs baseline: 2.3167x; 2.0064x over previous
//
#include <hip/hip_runtime.h>
#include <hip/hip_bf16.h>

// Shapes (fixed by setup_inputs): bs=8, v=2048, n=20, inc=64, outc=128, sup=2
#define BS    8
#define V     2048
#define NNB   20
#define INC   64
#define OUTC  128
#define SUP   2
#define NCOL  ((SUP + 1) * OUTC)   // 384
#define SCOL  (SUP * OUTC)         // 256
#define ROWS  (BS * V)             // 16384
#define XPAD  136                  // 128 + 8 bf16 pad -> 2-way-free b128 reads

using bf16x8 = __bf16 __attribute__((ext_vector_type(8)));
using bf16x4 = __bf16 __attribute__((ext_vector_type(4)));
using f32x4  = float  __attribute__((ext_vector_type(4)));
using f32x2  = float  __attribute__((ext_vector_type(2)));
using i32x4  = int    __attribute__((ext_vector_type(4)));
using u16x4  = unsigned short __attribute__((ext_vector_type(4)));

#if __has_builtin(__builtin_elementwise_fma)
static __device__ inline f32x2 efma(f32x2 a, f32x2 b, f32x2 c) { return __builtin_elementwise_fma(a, b, c); }
#else
static __device__ inline f32x2 efma(f32x2 a, f32x2 b, f32x2 c) {
    f32x2 r; r[0] = fmaf(a[0], b[0], c[0]); r[1] = fmaf(a[1], b[1], c[1]); return r;
}
#endif
#if __has_builtin(__builtin_elementwise_max)
static __device__ inline f32x2 emax(f32x2 a, f32x2 b) { return __builtin_elementwise_max(a, b); }
#else
static __device__ inline f32x2 emax(f32x2 a, f32x2 b) {
    f32x2 r; r[0] = fmaxf(a[0], b[0]); r[1] = fmaxf(a[1], b[1]); return r;
}
#endif

static __device__ inline bf16x8 cvt8(f32x4 lo, f32x4 hi) {
    bf16x8 r;
    r[0] = (__bf16)lo[0]; r[1] = (__bf16)lo[1]; r[2] = (__bf16)lo[2]; r[3] = (__bf16)lo[3];
    r[4] = (__bf16)hi[0]; r[5] = (__bf16)hi[1]; r[6] = (__bf16)hi[2]; r[7] = (__bf16)hi[3];
    return r;
}

// bf16 (raw u16) -> f32: value = bits << 16
static __device__ inline float b2f(unsigned short u) {
    union { unsigned int i; float f; } c; c.i = ((unsigned int)u) << 16; return c.f;
}

// ---------------------------------------------------------------------------
// K0: prep — WTb bf16 [384][64], Wm1b bf16 [128][128], w2 = Wm2 @ u,
//     u[k] = relu(dw[k]) + relu(dw[128+k])  (valid since dmax >= 0).
// ---------------------------------------------------------------------------
__global__ __launch_bounds__(256) void k_prep(const float* __restrict__ W,
                                              const float* __restrict__ Wm,
                                              const float* __restrict__ dw,
                                              __bf16* __restrict__ WTb,
                                              __bf16* __restrict__ Wm1b,
                                              float* __restrict__ w2) {
    const int b = blockIdx.x;
    if (b < 96) {                       // W [64][384] -> WTb [384][64], coalesced writes
        const int idx = b * 256 + threadIdx.x;      // < 24576
        const int c = idx >> 6, k = idx & 63;
        WTb[idx] = (__bf16)W[k * NCOL + c];
    } else if (b < 160) {               // Wm[:, :128] -> bf16 [o][k]
        const int idx = (b - 96) * 256 + threadIdx.x;   // < 16384
        const int o = idx >> 7, k = idx & 127;
        Wm1b[idx] = (__bf16)Wm[o * SCOL + k];
    } else {                            // u + w2
        __shared__ float u[OUTC];
        const int t = threadIdx.x;
        if (t < OUTC) u[t] = fmaxf(dw[t], 0.f) + fmaxf(dw[OUTC + t], 0.f);
        __syncthreads();
        if (t < OUTC) {
            float s = 0.f;
            for (int k = 0; k < OUTC; ++k) s = fmaf(Wm[t * SCOL + OUTC + k], u[k], s);
            w2[t] = s;
        }
    }
}

// ---------------------------------------------------------------------------
// K1: feat = fm @ W + bias (MFMA bf16). Block = 4 waves, 32 rows x 384 cols.
// center -> f32, support -> bf16 supb (512-B rows, line-aligned).
// ---------------------------------------------------------------------------
__global__ __launch_bounds__(256) void k_feat(const float* __restrict__ fm,
                                              const __bf16* __restrict__ WTb,
                                              const float* __restrict__ bias,
                                              float* __restrict__ center,
                                              __bf16* __restrict__ supb) {
    const int row0 = blockIdx.x * 32;
    const int wid = threadIdx.x >> 6, lane = threadIdx.x & 63;
    const int ln = lane & 15, lg = lane >> 4;
    const int cbase = wid * 96;

    bf16x8 a[2][2];
#pragma unroll
    for (int rs = 0; rs < 2; ++rs) {
        const float* ap = fm + (size_t)(row0 + rs * 16 + ln) * INC + lg * 8;
        a[rs][0] = cvt8(*(const f32x4*)(ap +  0), *(const f32x4*)(ap +  4));
        a[rs][1] = cvt8(*(const f32x4*)(ap + 32), *(const f32x4*)(ap + 36));
    }

    f32x4 acc[2][6];
#pragma unroll
    for (int t = 0; t < 6; ++t) {
        const float bb = bias[cbase + t * 16 + ln];
        acc[0][t] = (f32x4){bb, bb, bb, bb};
        acc[1][t] = acc[0][t];
    }

    const __bf16* bp = WTb + (size_t)(cbase + ln) * INC + lg * 8;
#pragma unroll
    for (int t = 0; t < 6; ++t) {
        const bf16x8 b0 = *(const bf16x8*)(bp + t * 16 * INC);
        const bf16x8 b1 = *(const bf16x8*)(bp + t * 16 * INC + 32);
        acc[0][t] = __builtin_amdgcn_mfma_f32_16x16x32_bf16(a[0][0], b0, acc[0][t], 0, 0, 0);
        acc[0][t] = __builtin_amdgcn_mfma_f32_16x16x32_bf16(a[0][1], b1, acc[0][t], 0, 0, 0);
        acc[1][t] = __builtin_amdgcn_mfma_f32_16x16x32_bf16(a[1][0], b0, acc[1][t], 0, 0, 0);
        acc[1][t] = __builtin_amdgcn_mfma_f32_16x16x32_bf16(a[1][1], b1, acc[1][t], 0, 0, 0);
    }

    // C: col = lane&15, row = (lane>>4)*4 + r
#pragma unroll
    for (int rs = 0; rs < 2; ++rs) {
        const int r0 = row0 + rs * 16 + lg * 4;
#pragma unroll
        for (int t = 0; t < 6; ++t) {
            const int col = cbase + t * 16 + ln;
            if (col < OUTC) {
#pragma unroll
                for (int r = 0; r < 4; ++r)
                    center[(size_t)(r0 + r) * OUTC + col] = acc[rs][t][r];
            } else {
                const int sc = col - OUTC;
#pragma unroll
                for (int r = 0; r < 4; ++r)
                    supb[(size_t)(r0 + r) * SCOL + sc] = (__bf16)acc[rs][t][r];
            }
        }
    }
}

// ---------------------------------------------------------------------------
// K2 (merged neigh+out): block = 8 vertices, grid 2048.
// SINGLE-VARIABLE change vs R9 (28 us, 37% occ): half the block, double the
// grid. launch_bounds stays (256,4) so compiler keeps ~64 VGPR and the
// batched-load ILP (R11 lesson: (256,8) crushed VGPR to 32 -> serialized).
// At 64 VGPR + 4.6KB LDS, HW co-schedules ~8 small blocks/CU -> occ ~65%.
// Phase N: 4 waves x 2 vertices (32 lanes each); supb 512-B rows (line-
// aligned, R10-proven 15 MB fetch). Phase G: M=16 MFMA, 8 valid rows.
// batch = bid&7 XCD swizzle.
// ---------------------------------------------------------------------------
__global__ __launch_bounds__(256, 4) void k_no(const int*   __restrict__ nbr,
                                               const float* __restrict__ verts,
                                               const float* __restrict__ dirs,
                                               const float* __restrict__ center,
                                               const __bf16* __restrict__ supb,
                                               const __bf16* __restrict__ Wm1b,
                                               const float* __restrict__ w2,
                                               const float* __restrict__ mb,
                                               float* __restrict__ out) {
    const int bid   = blockIdx.x;
    const int batch = bid & 7;
    const int chunk = bid >> 3;            // 0..255
    const int u0    = chunk * 8;
    const int bV    = batch * V;
    const int tid   = threadIdx.x;
    const int wid   = tid >> 6;
    const int lane  = tid & 63;
    const int half  = lane >> 5;
    const int sl    = lane & 31;
    const int c0    = sl * 4;
    const int ln    = lane & 15, lg = lane >> 4;

    __shared__ __bf16 Xl[16][XPAD];        // rows 0..7 valid
    __shared__ float  dl[16];

    // ---- normalized spatial directions
    f32x4 A0 = *(const f32x4*)(dirs +            c0);
    f32x4 A1 = *(const f32x4*)(dirs + SCOL +     c0);
    f32x4 A2 = *(const f32x4*)(dirs + 2*SCOL +   c0);
    f32x4 B0 = *(const f32x4*)(dirs +            OUTC + c0);
    f32x4 B1 = *(const f32x4*)(dirs + SCOL +     OUTC + c0);
    f32x4 B2 = *(const f32x4*)(dirs + 2*SCOL +   OUTC + c0);
#pragma unroll
    for (int j = 0; j < 4; ++j) {
        float inv = __builtin_amdgcn_rsqf(fmaxf(fmaf(A0[j], A0[j], fmaf(A1[j], A1[j], A2[j]*A2[j])), 1e-24f));
        A0[j] *= inv; A1[j] *= inv; A2[j] *= inv;
        inv = __builtin_amdgcn_rsqf(fmaxf(fmaf(B0[j], B0[j], fmaf(B1[j], B1[j], B2[j]*B2[j])), 1e-24f));
        B0[j] *= inv; B1[j] *= inv; B2[j] *= inv;
    }
    const f32x2 ax0 = {A0[0], A0[1]}, ax1 = {A0[2], A0[3]};
    const f32x2 ay0 = {A1[0], A1[1]}, ay1 = {A1[2], A1[3]};
    const f32x2 az0 = {A2[0], A2[1]}, az1 = {A2[2], A2[3]};
    const f32x2 bx0 = {B0[0], B0[1]}, bx1 = {B0[2], B0[3]};
    const f32x2 by0 = {B1[0], B1[1]}, by1 = {B1[2], B1[3]};
    const f32x2 bz0 = {B2[0], B2[1]}, bz1 = {B2[2], B2[3]};
    const f32x2 zero = {0.f, 0.f};

    const __bf16* supBase = supb + (size_t)bV * SCOL + c0;

    // ---- Phase N: 2 vertices/wave, one pass
    {
        const int ul  = wid * 2 + half;        // 0..7
        const int row = bV + u0 + ul;

        const float vx = verts[row * 3 + 0];
        const float vy = verts[row * 3 + 1];
        const float vz = verts[row * 3 + 2];

        int gs[NNB];
        {
            const i32x4* np4 = reinterpret_cast<const i32x4*>(nbr + (size_t)row * NNB);
#pragma unroll
            for (int t = 0; t < 5; ++t) {
                const i32x4 g4 = np4[t];
                gs[t*4+0] = g4[0]; gs[t*4+1] = g4[1]; gs[t*4+2] = g4[2]; gs[t*4+3] = g4[3];
            }
        }

        f32x2 mA0 = {-INFINITY, -INFINITY}, mA1 = mA0, mB0 = mA0, mB1 = mA0;
        float d2max = 0.f;

#pragma unroll
        for (int t = 0; t < 4; ++t) {
            // issue 10 support gathers + 5 vertex reads for 5 neighbors
            u16x4 s0r[5], s1r[5];
            float px[5], py[5], pz[5];
#pragma unroll
            for (int q = 0; q < 5; ++q) {
                const int g = gs[t * 5 + q];
                const __bf16* sg = supBase + (size_t)g * SCOL;
                s0r[q] = *(const u16x4*)(sg);
                s1r[q] = *(const u16x4*)(sg + OUTC);
                const float* vp = verts + (size_t)(bV + g) * 3;
                px[q] = vp[0]; py[q] = vp[1]; pz[q] = vp[2];
            }
#pragma unroll
            for (int q = 0; q < 5; ++q) {
                const float dx = px[q] - vx, dy = py[q] - vy, dz = pz[q] - vz;
                const float d2 = fmaf(dx, dx, fmaf(dy, dy, dz * dz));
                d2max = fmaxf(d2max, d2);
                const float inv = __builtin_amdgcn_rsqf(fmaxf(d2, 1e-24f));  // == 1/max(dist,1e-12)
                const f32x2 nX = {dx * inv, dx * inv};
                const f32x2 nY = {dy * inv, dy * inv};
                const f32x2 nZ = {dz * inv, dz * inv};

                const f32x2 s0lo = {b2f(s0r[q][0]), b2f(s0r[q][1])};
                const f32x2 s0hi = {b2f(s0r[q][2]), b2f(s0r[q][3])};
                const f32x2 s1lo = {b2f(s1r[q][0]), b2f(s1r[q][1])};
                const f32x2 s1hi = {b2f(s1r[q][2]), b2f(s1r[q][3])};

                const f32x2 tA0 = emax(efma(nZ, az0, efma(nY, ay0, nX * ax0)), zero);
                const f32x2 tA1 = emax(efma(nZ, az1, efma(nY, ay1, nX * ax1)), zero);
                const f32x2 tB0 = emax(efma(nZ, bz0, efma(nY, by0, nX * bx0)), zero);
                const f32x2 tB1 = emax(efma(nZ, bz1, efma(nY, by1, nX * bx1)), zero);
                mA0 = emax(mA0, tA0 * s0lo);
                mA1 = emax(mA1, tA1 * s0hi);
                mB0 = emax(mB0, tB0 * s1lo);
                mB1 = emax(mB1, tB1 * s1hi);
            }
        }

        const f32x4 cc = *(const f32x4*)(center + (size_t)row * OUTC + c0);
        const f32x2 f01 = (f32x2){cc[0], cc[1]} + mA0 + mB0;
        const f32x2 f23 = (f32x2){cc[2], cc[3]} + mA1 + mB1;
        bf16x4 fx;
        fx[0] = (__bf16)f01[0]; fx[1] = (__bf16)f01[1];
        fx[2] = (__bf16)f23[0]; fx[3] = (__bf16)f23[1];
        *(bf16x4*)(&Xl[ul][c0]) = fx;
        if (sl == 0) dl[ul] = sqrtf(d2max);
    }
    __syncthreads();

    // ---- Phase G: out = Xl @ Wm1b^T + dmax*w2 + mb (MFMA, K=128)
    // wave wid -> cols wid*32..+31 (2 tiles). A rows 8-15 are garbage
    // (never stored; MFMA output rows are independent).
    {
        const int cb = wid * 32;

        bf16x8 a[4];
#pragma unroll
        for (int kf = 0; kf < 4; ++kf)
            a[kf] = *(const bf16x8*)(&Xl[ln][lg * 8 + kf * 32]);

        f32x4 acc[2];
        acc[0] = (f32x4)0.f; acc[1] = (f32x4)0.f;

        const __bf16* bp = Wm1b + (size_t)(cb + ln) * OUTC + lg * 8;
#pragma unroll
        for (int t = 0; t < 2; ++t) {
#pragma unroll
            for (int kf = 0; kf < 4; ++kf) {
                const bf16x8 b = *(const bf16x8*)(bp + t * 16 * OUTC + kf * 32);
                acc[t] = __builtin_amdgcn_mfma_f32_16x16x32_bf16(a[kf], b, acc[t], 0, 0, 0);
            }
        }

        if (lg < 2) {                       // valid output rows 0..7
            float dm[4];
#pragma unroll
            for (int r = 0; r < 4; ++r) dm[r] = dl[lg * 4 + r];

            const int rowg0 = bV + u0 + lg * 4;
#pragma unroll
            for (int t = 0; t < 2; ++t) {
                const int col = cb + t * 16 + ln;
                const float w2c = w2[col];
                const float bb  = mb[col];
#pragma unroll
                for (int r = 0; r < 4; ++r)
                    out[(size_t)(rowg0 + r) * OUTC + col] = fmaf(dm[r], w2c, acc[t][r] + bb);
            }
        }
    }
}

// ---------------------------------------------------------------------------
extern "C" void kernel_launch(void* const* d_in, const int* in_sizes, int n_in,
                              void* d_out, int out_size, void* d_ws, size_t ws_size,
                              hipStream_t stream) {
    const int*   nbr   = (const int*)  d_in[0];
    const float* verts = (const float*)d_in[1];
    const float* fm    = (const float*)d_in[2];
    const float* W     = (const float*)d_in[3];
    const float* bias  = (const float*)d_in[4];
    const float* dirs  = (const float*)d_in[5];
    const float* dw    = (const float*)d_in[6];
    const float* Wm    = (const float*)d_in[7];
    const float* mb    = (const float*)d_in[8];
    float* out = (float*)d_out;

    // workspace layout (all 16B-aligned)
    float*  center  = (float*)d_ws;                               // 16384*128 f32
    __bf16* supb    = (__bf16*)(center + (size_t)ROWS * OUTC);    // 16384*256 bf16
    __bf16* WTb     = supb + (size_t)ROWS * SCOL;                 // 384*64 bf16
    __bf16* Wm1b    = WTb + NCOL * INC;                           // 128*128 bf16
    float*  w2      = (float*)(Wm1b + OUTC * OUTC);               // 128 f32

    k_prep <<<161,        256, 0, stream>>>(W, Wm, dw, WTb, Wm1b, w2);
    k_feat <<<ROWS / 32,  256, 0, stream>>>(fm, WTb, bias, center, supb);
    k_no   <<<ROWS / 8,   256, 0, stream>>>(nbr, verts, dirs, center, supb, Wm1b, w2, mb, out);
}

// Round 13
// 120.807 us; speedup vs baseline: 2.3299x; 1.0057x over previous
//
#include <hip/hip_runtime.h>
#include <hip/hip_bf16.h>

// Shapes (fixed by setup_inputs): bs=8, v=2048, n=20, inc=64, outc=128, sup=2
#define BS    8
#define V     2048
#define NNB   20
#define INC   64
#define OUTC  128
#define SUP   2
#define NCOL  ((SUP + 1) * OUTC)   // 384
#define SCOL  (SUP * OUTC)         // 256
#define ROWS  (BS * V)             // 16384
#define XPAD  136                  // 128 + 8 bf16 pad -> 2-way-free b128 reads

using bf16x8 = __bf16 __attribute__((ext_vector_type(8)));
using bf16x4 = __bf16 __attribute__((ext_vector_type(4)));
using f32x4  = float  __attribute__((ext_vector_type(4)));
using f32x2  = float  __attribute__((ext_vector_type(2)));
using i32x4  = int    __attribute__((ext_vector_type(4)));
using u16x4  = unsigned short __attribute__((ext_vector_type(4)));

#if __has_builtin(__builtin_elementwise_fma)
static __device__ inline f32x2 efma(f32x2 a, f32x2 b, f32x2 c) { return __builtin_elementwise_fma(a, b, c); }
#else
static __device__ inline f32x2 efma(f32x2 a, f32x2 b, f32x2 c) {
    f32x2 r; r[0] = fmaf(a[0], b[0], c[0]); r[1] = fmaf(a[1], b[1], c[1]); return r;
}
#endif
#if __has_builtin(__builtin_elementwise_max)
static __device__ inline f32x2 emax(f32x2 a, f32x2 b) { return __builtin_elementwise_max(a, b); }
#else
static __device__ inline f32x2 emax(f32x2 a, f32x2 b) {
    f32x2 r; r[0] = fmaxf(a[0], b[0]); r[1] = fmaxf(a[1], b[1]); return r;
}
#endif

static __device__ inline bf16x8 cvt8(f32x4 lo, f32x4 hi) {
    bf16x8 r;
    r[0] = (__bf16)lo[0]; r[1] = (__bf16)lo[1]; r[2] = (__bf16)lo[2]; r[3] = (__bf16)lo[3];
    r[4] = (__bf16)hi[0]; r[5] = (__bf16)hi[1]; r[6] = (__bf16)hi[2]; r[7] = (__bf16)hi[3];
    return r;
}

// bf16 (raw u16) -> f32: value = bits << 16
static __device__ inline float b2f(unsigned short u) {
    union { unsigned int i; float f; } c; c.i = ((unsigned int)u) << 16; return c.f;
}

// ---------------------------------------------------------------------------
// K0: prep — WTb bf16 [384][64], Wm1b bf16 [128][128], w2 = Wm2 @ u,
//     u[k] = relu(dw[k]) + relu(dw[128+k])  (valid since dmax >= 0).
// ---------------------------------------------------------------------------
__global__ __launch_bounds__(256) void k_prep(const float* __restrict__ W,
                                              const float* __restrict__ Wm,
                                              const float* __restrict__ dw,
                                              __bf16* __restrict__ WTb,
                                              __bf16* __restrict__ Wm1b,
                                              float* __restrict__ w2) {
    const int b = blockIdx.x;
    if (b < 96) {                       // W [64][384] -> WTb [384][64], coalesced writes
        const int idx = b * 256 + threadIdx.x;      // < 24576
        const int c = idx >> 6, k = idx & 63;
        WTb[idx] = (__bf16)W[k * NCOL + c];
    } else if (b < 160) {               // Wm[:, :128] -> bf16 [o][k]
        const int idx = (b - 96) * 256 + threadIdx.x;   // < 16384
        const int o = idx >> 7, k = idx & 127;
        Wm1b[idx] = (__bf16)Wm[o * SCOL + k];
    } else {                            // u + w2
        __shared__ float u[OUTC];
        const int t = threadIdx.x;
        if (t < OUTC) u[t] = fmaxf(dw[t], 0.f) + fmaxf(dw[OUTC + t], 0.f);
        __syncthreads();
        if (t < OUTC) {
            float s = 0.f;
            for (int k = 0; k < OUTC; ++k) s = fmaf(Wm[t * SCOL + OUTC + k], u[k], s);
            w2[t] = s;
        }
    }
}

// ---------------------------------------------------------------------------
// K1: feat = fm @ W + bias (MFMA bf16). Block = 4 waves, 32 rows x 384 cols.
// center -> f32, support -> bf16 supb (512-B rows, line-aligned).
// ---------------------------------------------------------------------------
__global__ __launch_bounds__(256) void k_feat(const float* __restrict__ fm,
                                              const __bf16* __restrict__ WTb,
                                              const float* __restrict__ bias,
                                              float* __restrict__ center,
                                              __bf16* __restrict__ supb) {
    const int row0 = blockIdx.x * 32;
    const int wid = threadIdx.x >> 6, lane = threadIdx.x & 63;
    const int ln = lane & 15, lg = lane >> 4;
    const int cbase = wid * 96;

    bf16x8 a[2][2];
#pragma unroll
    for (int rs = 0; rs < 2; ++rs) {
        const float* ap = fm + (size_t)(row0 + rs * 16 + ln) * INC + lg * 8;
        a[rs][0] = cvt8(*(const f32x4*)(ap +  0), *(const f32x4*)(ap +  4));
        a[rs][1] = cvt8(*(const f32x4*)(ap + 32), *(const f32x4*)(ap + 36));
    }

    f32x4 acc[2][6];
#pragma unroll
    for (int t = 0; t < 6; ++t) {
        const float bb = bias[cbase + t * 16 + ln];
        acc[0][t] = (f32x4){bb, bb, bb, bb};
        acc[1][t] = acc[0][t];
    }

    const __bf16* bp = WTb + (size_t)(cbase + ln) * INC + lg * 8;
#pragma unroll
    for (int t = 0; t < 6; ++t) {
        const bf16x8 b0 = *(const bf16x8*)(bp + t * 16 * INC);
        const bf16x8 b1 = *(const bf16x8*)(bp + t * 16 * INC + 32);
        acc[0][t] = __builtin_amdgcn_mfma_f32_16x16x32_bf16(a[0][0], b0, acc[0][t], 0, 0, 0);
        acc[0][t] = __builtin_amdgcn_mfma_f32_16x16x32_bf16(a[0][1], b1, acc[0][t], 0, 0, 0);
        acc[1][t] = __builtin_amdgcn_mfma_f32_16x16x32_bf16(a[1][0], b0, acc[1][t], 0, 0, 0);
        acc[1][t] = __builtin_amdgcn_mfma_f32_16x16x32_bf16(a[1][1], b1, acc[1][t], 0, 0, 0);
    }

    // C: col = lane&15, row = (lane>>4)*4 + r
#pragma unroll
    for (int rs = 0; rs < 2; ++rs) {
        const int r0 = row0 + rs * 16 + lg * 4;
#pragma unroll
        for (int t = 0; t < 6; ++t) {
            const int col = cbase + t * 16 + ln;
            if (col < OUTC) {
#pragma unroll
                for (int r = 0; r < 4; ++r)
                    center[(size_t)(r0 + r) * OUTC + col] = acc[rs][t][r];
            } else {
                const int sc = col - OUTC;
#pragma unroll
                for (int r = 0; r < 4; ++r)
                    supb[(size_t)(r0 + r) * SCOL + sc] = (__bf16)acc[rs][t][r];
            }
        }
    }
}

// ---------------------------------------------------------------------------
// K2 (merged neigh+out): R9 geometry (block = 16 vertices, grid 1024) with an
// explicitly software-pipelined gather loop: double-buffered 4-neighbor
// batches (A/B), batch t+1's loads issued before batch t's math. All buffer
// indices compile-time static. launch_bounds(256,4) -> 128-VGPR budget.
// batch = bid&7 XCD swizzle.
// ---------------------------------------------------------------------------
__global__ __launch_bounds__(256, 4) void k_no(const int*   __restrict__ nbr,
                                               const float* __restrict__ verts,
                                               const float* __restrict__ dirs,
                                               const float* __restrict__ center,
                                               const __bf16* __restrict__ supb,
                                               const __bf16* __restrict__ Wm1b,
                                               const float* __restrict__ w2,
                                               const float* __restrict__ mb,
                                               float* __restrict__ out) {
    const int bid   = blockIdx.x;
    const int batch = bid & 7;
    const int chunk = bid >> 3;            // 0..127
    const int u0    = chunk * 16;
    const int bV    = batch * V;
    const int tid   = threadIdx.x;
    const int wid   = tid >> 6;
    const int lane  = tid & 63;
    const int half  = lane >> 5;
    const int sl    = lane & 31;
    const int c0    = sl * 4;
    const int ln    = lane & 15, lg = lane >> 4;

    __shared__ __bf16 Xl[16][XPAD];        // 4.25 KB
    __shared__ float  dl[16];

    // ---- normalized spatial directions (reused across both passes)
    f32x4 A0 = *(const f32x4*)(dirs +            c0);
    f32x4 A1 = *(const f32x4*)(dirs + SCOL +     c0);
    f32x4 A2 = *(const f32x4*)(dirs + 2*SCOL +   c0);
    f32x4 B0 = *(const f32x4*)(dirs +            OUTC + c0);
    f32x4 B1 = *(const f32x4*)(dirs + SCOL +     OUTC + c0);
    f32x4 B2 = *(const f32x4*)(dirs + 2*SCOL +   OUTC + c0);
#pragma unroll
    for (int j = 0; j < 4; ++j) {
        float inv = __builtin_amdgcn_rsqf(fmaxf(fmaf(A0[j], A0[j], fmaf(A1[j], A1[j], A2[j]*A2[j])), 1e-24f));
        A0[j] *= inv; A1[j] *= inv; A2[j] *= inv;
        inv = __builtin_amdgcn_rsqf(fmaxf(fmaf(B0[j], B0[j], fmaf(B1[j], B1[j], B2[j]*B2[j])), 1e-24f));
        B0[j] *= inv; B1[j] *= inv; B2[j] *= inv;
    }
    const f32x2 ax0 = {A0[0], A0[1]}, ax1 = {A0[2], A0[3]};
    const f32x2 ay0 = {A1[0], A1[1]}, ay1 = {A1[2], A1[3]};
    const f32x2 az0 = {A2[0], A2[1]}, az1 = {A2[2], A2[3]};
    const f32x2 bx0 = {B0[0], B0[1]}, bx1 = {B0[2], B0[3]};
    const f32x2 by0 = {B1[0], B1[1]}, by1 = {B1[2], B1[3]};
    const f32x2 bz0 = {B2[0], B2[1]}, bz1 = {B2[2], B2[3]};
    const f32x2 zero = {0.f, 0.f};

    const __bf16* supBase = supb + (size_t)bV * SCOL + c0;

    // ---- Phase N: 2 passes x 2 vertices/wave, pipelined 4-neighbor batches
#pragma unroll
    for (int p = 0; p < 2; ++p) {
        const int ul  = p * 8 + wid * 2 + half;      // 0..15
        const int row = bV + u0 + ul;

        const float vx = verts[row * 3 + 0];
        const float vy = verts[row * 3 + 1];
        const float vz = verts[row * 3 + 2];

        int gs[NNB];
        {
            const i32x4* np4 = reinterpret_cast<const i32x4*>(nbr + (size_t)row * NNB);
#pragma unroll
            for (int t = 0; t < 5; ++t) {
                const i32x4 g4 = np4[t];
                gs[t*4+0] = g4[0]; gs[t*4+1] = g4[1]; gs[t*4+2] = g4[2]; gs[t*4+3] = g4[3];
            }
        }

        f32x2 mA0 = {-INFINITY, -INFINITY}, mA1 = mA0, mB0 = mA0, mB1 = mA0;
        float d2max = 0.f;

        // double-buffered batches of 4 neighbors
        u16x4 As0[4], As1[4]; float Ax[4], Ay[4], Az[4];
        u16x4 Bs0[4], Bs1[4]; float Bx[4], By[4], Bz[4];

#define LOADB(P, base)                                                        \
        _Pragma("unroll")                                                     \
        for (int q = 0; q < 4; ++q) {                                         \
            const int g = gs[(base) + q];                                     \
            const __bf16* sg = supBase + (size_t)g * SCOL;                    \
            P##s0[q] = *(const u16x4*)(sg);                                   \
            P##s1[q] = *(const u16x4*)(sg + OUTC);                            \
            const float* vp = verts + (size_t)(bV + g) * 3;                   \
            P##x[q] = vp[0]; P##y[q] = vp[1]; P##z[q] = vp[2];                \
        }

#define MATHB(P)                                                              \
        _Pragma("unroll")                                                     \
        for (int q = 0; q < 4; ++q) {                                         \
            const float dx = P##x[q] - vx, dy = P##y[q] - vy, dz = P##z[q] - vz; \
            const float d2 = fmaf(dx, dx, fmaf(dy, dy, dz * dz));             \
            d2max = fmaxf(d2max, d2);                                         \
            const float inv = __builtin_amdgcn_rsqf(fmaxf(d2, 1e-24f));       \
            const f32x2 nX = {dx * inv, dx * inv};                            \
            const f32x2 nY = {dy * inv, dy * inv};                            \
            const f32x2 nZ = {dz * inv, dz * inv};                            \
            const f32x2 s0lo = {b2f(P##s0[q][0]), b2f(P##s0[q][1])};          \
            const f32x2 s0hi = {b2f(P##s0[q][2]), b2f(P##s0[q][3])};          \
            const f32x2 s1lo = {b2f(P##s1[q][0]), b2f(P##s1[q][1])};          \
            const f32x2 s1hi = {b2f(P##s1[q][2]), b2f(P##s1[q][3])};          \
            const f32x2 tA0 = emax(efma(nZ, az0, efma(nY, ay0, nX * ax0)), zero); \
            const f32x2 tA1 = emax(efma(nZ, az1, efma(nY, ay1, nX * ax1)), zero); \
            const f32x2 tB0 = emax(efma(nZ, bz0, efma(nY, by0, nX * bx0)), zero); \
            const f32x2 tB1 = emax(efma(nZ, bz1, efma(nY, by1, nX * bx1)), zero); \
            mA0 = emax(mA0, tA0 * s0lo);                                      \
            mA1 = emax(mA1, tA1 * s0hi);                                      \
            mB0 = emax(mB0, tB0 * s1lo);                                      \
            mB1 = emax(mB1, tB1 * s1hi);                                      \
        }

        LOADB(A, 0)          // batch 0 in flight
        LOADB(B, 4)          // batch 1 in flight
        MATHB(A)             // consume 0  (batch 1 covering latency)
        LOADB(A, 8)          // batch 2 in flight
        MATHB(B)             // consume 1
        LOADB(B, 12)         // batch 3 in flight
        MATHB(A)             // consume 2
        LOADB(A, 16)         // batch 4 in flight
        MATHB(B)             // consume 3
        MATHB(A)             // consume 4

#undef LOADB
#undef MATHB

        const f32x4 cc = *(const f32x4*)(center + (size_t)row * OUTC + c0);
        const f32x2 f01 = (f32x2){cc[0], cc[1]} + mA0 + mB0;
        const f32x2 f23 = (f32x2){cc[2], cc[3]} + mA1 + mB1;
        bf16x4 fx;
        fx[0] = (__bf16)f01[0]; fx[1] = (__bf16)f01[1];
        fx[2] = (__bf16)f23[0]; fx[3] = (__bf16)f23[1];
        *(bf16x4*)(&Xl[ul][c0]) = fx;
        if (sl == 0) dl[ul] = sqrtf(d2max);
    }
    __syncthreads();

    // ---- Phase G: out = Xl @ Wm1b^T + dmax*w2 + mb (MFMA, K=128)
    // wave wid -> cols wid*32..+31 (2 tiles of 16), rows 0..15.
    {
        const int cb = wid * 32;

        bf16x8 a[4];
#pragma unroll
        for (int kf = 0; kf < 4; ++kf)
            a[kf] = *(const bf16x8*)(&Xl[ln][lg * 8 + kf * 32]);

        f32x4 acc[2];
        acc[0] = (f32x4)0.f; acc[1] = (f32x4)0.f;

        const __bf16* bp = Wm1b + (size_t)(cb + ln) * OUTC + lg * 8;
#pragma unroll
        for (int t = 0; t < 2; ++t) {
#pragma unroll
            for (int kf = 0; kf < 4; ++kf) {
                const bf16x8 b = *(const bf16x8*)(bp + t * 16 * OUTC + kf * 32);
                acc[t] = __builtin_amdgcn_mfma_f32_16x16x32_bf16(a[kf], b, acc[t], 0, 0, 0);
            }
        }

        float dm[4];
#pragma unroll
        for (int r = 0; r < 4; ++r) dm[r] = dl[lg * 4 + r];

        const int rowg0 = bV + u0 + lg * 4;
#pragma unroll
        for (int t = 0; t < 2; ++t) {
            const int col = cb + t * 16 + ln;
            const float w2c = w2[col];
            const float bb  = mb[col];
#pragma unroll
            for (int r = 0; r < 4; ++r)
                out[(size_t)(rowg0 + r) * OUTC + col] = fmaf(dm[r], w2c, acc[t][r] + bb);
        }
    }
}

// ---------------------------------------------------------------------------
extern "C" void kernel_launch(void* const* d_in, const int* in_sizes, int n_in,
                              void* d_out, int out_size, void* d_ws, size_t ws_size,
                              hipStream_t stream) {
    const int*   nbr   = (const int*)  d_in[0];
    const float* verts = (const float*)d_in[1];
    const float* fm    = (const float*)d_in[2];
    const float* W     = (const float*)d_in[3];
    const float* bias  = (const float*)d_in[4];
    const float* dirs  = (const float*)d_in[5];
    const float* dw    = (const float*)d_in[6];
    const float* Wm    = (const float*)d_in[7];
    const float* mb    = (const float*)d_in[8];
    float* out = (float*)d_out;

    // workspace layout (all 16B-aligned)
    float*  center  = (float*)d_ws;                               // 16384*128 f32
    __bf16* supb    = (__bf16*)(center + (size_t)ROWS * OUTC);    // 16384*256 bf16
    __bf16* WTb     = supb + (size_t)ROWS * SCOL;                 // 384*64 bf16
    __bf16* Wm1b    = WTb + NCOL * INC;                           // 128*128 bf16
    float*  w2      = (float*)(Wm1b + OUTC * OUTC);               // 128 f32

    k_prep <<<161,        256, 0, stream>>>(W, Wm, dw, WTb, Wm1b, w2);
    k_feat <<<ROWS / 32,  256, 0, stream>>>(fm, WTb, bias, center, supb);
    k_no   <<<ROWS / 16,  256, 0, stream>>>(nbr, verts, dirs, center, supb, Wm1b, w2, mb, out);
}